// Round 14
// baseline (1992.003 us; speedup 1.0000x reference)
//
#include <hip/hip_runtime.h>
#include <hip/hip_bf16.h>

typedef unsigned int u32;
typedef unsigned short u16;

#define MTOT 31936      // B*N = 64*499
#define NN 499
#define BB 64

// ---------- helpers ----------
__device__ __forceinline__ float lo16(u32 u){ return __uint_as_float(u << 16); }
__device__ __forceinline__ float hi16(u32 u){ return __uint_as_float(u & 0xffff0000u); }
__device__ __forceinline__ float bf2f(u16 u){ return __uint_as_float(((u32)u) << 16); }
__device__ __forceinline__ u16 f2bf(float f){
  u32 x = __float_as_uint(f);
  u32 r = (x + 0x7fffu + ((x >> 16) & 1u)) >> 16;   // RNE
  return (u16)r;
}
__device__ __forceinline__ float sigf(float x){ return 1.f / (1.f + __expf(-x)); }
__device__ __forceinline__ float tanh_(float x){ return 2.f * sigf(2.f * x) - 1.f; }
__device__ __forceinline__ float wred(float v){
  #pragma unroll
  for (int off = 32; off; off >>= 1) v += __shfl_down(v, off, 64);
  return v;
}

// packed bf16 pair dot: acc += lo(w)*lo(h) + hi(w)*hi(h)
typedef __attribute__((ext_vector_type(2))) __bf16 bf16x2;
#if __has_builtin(__builtin_amdgcn_fdot2_f32_bf16)
__device__ __forceinline__ float dot2bf(u32 w, u32 h, float acc){
  union { u32 u; bf16x2 v; } uw, uh;
  uw.u = w; uh.u = h;
  return __builtin_amdgcn_fdot2_f32_bf16(uw.v, uh.v, acc, false);
}
#else
__device__ __forceinline__ float dot2bf(u32 w, u32 h, float acc){
  return acc + lo16(w) * lo16(h) + hi16(w) * hi16(h);
}
#endif

// pack two f32 -> u32 of two bf16 (RNE)
#if __has_builtin(__builtin_amdgcn_cvt_pk_bf16_f32)
__device__ __forceinline__ u32 pk2bf(float a, float b){
  union { bf16x2 v; u32 u; } r;
  r.v = __builtin_amdgcn_cvt_pk_bf16_f32(a, b);
  return r.u;
}
#else
__device__ __forceinline__ u32 pk2bf(float a, float b){
  return (u32)f2bf(a) | ((u32)f2bf(b) << 16);
}
#endif

// ---------- MFMA plumbing (16x16x32 bf16) ----------
// A-frag: lane holds A[m=lane&15][k=(lane>>4)*8 + j], j=0..7  (8 bf16 = uint4)
// B-frag: lane holds B[k=(lane>>4)*8 + j][n=lane&15]
// C/D   : reg r at row=(lane>>4)*4+r, col=lane&15
typedef __attribute__((ext_vector_type(8))) short bfrag8;
typedef __attribute__((ext_vector_type(4))) float f4_t;
union FragU { uint4 u; bfrag8 s; };

__device__ __forceinline__ f4_t mfma16(FragU a, FragU b, f4_t c){
  return __builtin_amdgcn_mfma_f32_16x16x32_bf16(a.s, b.s, c, 0, 0, 0);
}

// shared GEMM core: 64x64 tile, 4 waves x (32x32), double-buffered LDS A, direct-global B frags
template <typename AL>
__device__ __forceinline__ void gemm_core(int K32, const uint4* __restrict__ Bpack,
                                          f4_t (&acc)[2][2], AL aload){
  __shared__ __align__(16) uint4 As[2][256];
  const int tid = threadIdx.x;
  const int wave = tid >> 6, lane = tid & 63;
  const int w2 = (wave >> 1) * 2;
  const uint4* Bp0 = Bpack + ((size_t)(blockIdx.y * 4 + (wave & 1) * 2) * K32) * 64 + lane;
  const uint4* Bp1 = Bp0 + (size_t)K32 * 64;
  int buf = 0;
  for (int kt = 0; kt < K32; kt++){
    FragU b0, b1;
    b0.u = Bp0[kt * 64];
    b1.u = Bp1[kt * 64];
    As[buf][tid] = aload(kt);
    __syncthreads();
    FragU a0, a1;
    a0.u = As[buf][w2 * 64 + lane];
    a1.u = As[buf][w2 * 64 + 64 + lane];
    acc[0][0] = mfma16(a0, b0, acc[0][0]);
    acc[0][1] = mfma16(a0, b1, acc[0][1]);
    acc[1][0] = mfma16(a1, b0, acc[1][0]);
    acc[1][1] = mfma16(a1, b1, acc[1][1]);
    buf ^= 1;
  }
}

// ---------- prep: pack weight matrix into B-fragment-layout bf16 chunks ----------
// chunk c: nt=c/(K32*64), kt=(c/64)%K32, l=c&63 -> holds B[k=kt*32+(l>>4)*8+j][n=nt*16+(l&15)]
// trans=0: B[k][n] = W[k*N+n] ; trans=1: B[k][n] = W[n*K+k]
__global__ __launch_bounds__(256) void k_packB(const float* __restrict__ W, u16* __restrict__ out,
                                               int K, int N, int trans){
  int c = blockIdx.x * 256 + threadIdx.x;
  int K32 = K >> 5;
  int total = (N >> 4) * K32 * 64;
  if (c >= total) return;
  int l = c & 63;
  int rem = c >> 6;
  int kt = rem % K32, nt = rem / K32;
  int n = nt * 16 + (l & 15);
  int kb = kt * 32 + (l >> 4) * 8;
  u32 ov[4];
  #pragma unroll
  for (int j2 = 0; j2 < 4; j2++){
    int k = kb + j2 * 2;
    float f0 = trans ? W[(size_t)n * K + k]     : W[(size_t)k * N + n];
    float f1 = trans ? W[(size_t)n * K + k + 1] : W[(size_t)(k + 1) * N + n];
    ov[j2] = pk2bf(f0, f1);
  }
  uint4 o; o.x = ov[0]; o.y = ov[1]; o.z = ov[2]; o.w = ov[3];
  *(uint4*)(out + (size_t)c * 8) = o;
}

// ---------- CSR build (chain graph, in-degree <= 3) ----------
__global__ void k_csr(const int* __restrict__ src, const int* __restrict__ dst, int E,
                      int* __restrict__ deg, int* __restrict__ insrc){
  int tid = threadIdx.x;
  for (int i = tid; i < NN; i += 256) deg[i] = 0;
  for (int i = tid; i < NN * 4; i += 256) insrc[i] = 0;
  __syncthreads();
  for (int e = tid; e < E; e += 256){
    int d = dst[e];
    int slot = atomicAdd(&deg[d], 1);
    if (slot < 4) insrc[d * 4 + slot] = src[e];
  }
}

// ---------- pack W_hh [1024,256] f32 -> bf16 uint4 chunks: whh4[kc*1024 + j] = row j, k = kc*8..+7
__global__ void k_packwhh(const float* __restrict__ Whh, uint4* __restrict__ whh4){
  int idx = blockIdx.x * 256 + threadIdx.x;      // 32768 total
  int j = idx & 1023, kc = idx >> 10;
  const float* w = Whh + (size_t)j * 256 + kc * 8;
  float4 w0 = *(const float4*)w;
  float4 w1 = *(const float4*)(w + 4);
  uint4 o;
  o.x = pk2bf(w0.x, w0.y);
  o.y = pk2bf(w0.z, w0.w);
  o.z = pk2bf(w1.x, w1.y);
  o.w = pk2bf(w1.z, w1.w);
  whh4[kc * 1024 + j] = o;
}

// ---------- GEMM 1 (MFMA): x0 = concat(emb_p[p], emb_aff[aff]) @ W_affcat + b ; K=512, N=256, f32 out
__global__ __launch_bounds__(256) void k_affcat_m(
    const float* __restrict__ emb_p, const float* __restrict__ emb_aff,
    const int* __restrict__ p, const int* __restrict__ aff,
    const uint4* __restrict__ Bpack, const float* __restrict__ bias, float* __restrict__ C){
  const int tid = threadIdx.x;
  const int mBase = blockIdx.x * 64, nBase = blockIdx.y * 64;
  const int ls = tid & 63;
  const int gm = mBase + (tid >> 6) * 16 + (ls & 15);
  const int kqoff = (ls >> 4) * 8;
  const float* rp = emb_p + (size_t)p[gm] * 256 + kqoff;
  const float* ra = emb_aff + (size_t)aff[gm] * 256 + kqoff;
  f4_t acc[2][2] = {};
  gemm_core(16, Bpack, acc, [&](int kt) -> uint4 {
    int kb = kt * 32;
    const float* s = (kb < 256) ? (rp + kb) : (ra + kb - 256);
    float4 v0 = *(const float4*)s;
    float4 v1 = *(const float4*)(s + 4);
    uint4 o; o.x = pk2bf(v0.x, v0.y); o.y = pk2bf(v0.z, v0.w);
    o.z = pk2bf(v1.x, v1.y); o.w = pk2bf(v1.z, v1.w);
    return o;
  });
  const int wave = tid >> 6, lane = tid & 63;
  const int rbase = mBase + (wave >> 1) * 32 + ((lane >> 4) << 2);
  const int cbase = nBase + (wave & 1) * 32 + (lane & 15);
  float b0 = bias[cbase], b1 = bias[cbase + 16];
  #pragma unroll
  for (int i = 0; i < 2; i++)
    #pragma unroll
    for (int r = 0; r < 4; r++){
      int row = rbase + i * 16 + r;
      C[(size_t)row * 256 + cbase]      = acc[i][0][r] + b0;
      C[(size_t)row * 256 + cbase + 16] = acc[i][1][r] + b1;
    }
}

// ---------- GEMM 2 (MFMA): h1 = x0 @ W_g1 ; K=256, N=1024, bf16 out
__global__ __launch_bounds__(256) void k_h1_m(const float* __restrict__ A,
                                              const uint4* __restrict__ Bpack,
                                              u16* __restrict__ Cb){
  const int tid = threadIdx.x;
  const int mBase = blockIdx.x * 64, nBase = blockIdx.y * 64;
  const int ls = tid & 63;
  const int gm = mBase + (tid >> 6) * 16 + (ls & 15);
  const float* ra = A + (size_t)gm * 256 + (ls >> 4) * 8;
  f4_t acc[2][2] = {};
  gemm_core(8, Bpack, acc, [&](int kt) -> uint4 {
    const float* s = ra + kt * 32;
    float4 v0 = *(const float4*)s;
    float4 v1 = *(const float4*)(s + 4);
    uint4 o; o.x = pk2bf(v0.x, v0.y); o.y = pk2bf(v0.z, v0.w);
    o.z = pk2bf(v1.x, v1.y); o.w = pk2bf(v1.z, v1.w);
    return o;
  });
  const int wave = tid >> 6, lane = tid & 63;
  const int rbase = mBase + (wave >> 1) * 32 + ((lane >> 4) << 2);
  const int cbase = nBase + (wave & 1) * 32 + (lane & 15);
  #pragma unroll
  for (int i = 0; i < 2; i++)
    #pragma unroll
    for (int r = 0; r < 4; r++){
      int row = rbase + i * 16 + r;
      Cb[(size_t)row * 1024 + cbase]      = f2bf(acc[i][0][r]);
      Cb[(size_t)row * 1024 + cbase + 16] = f2bf(acc[i][1][r]);
    }
}

// ---------- GEMM 3 (MFMA): h2 = g1out @ W_g2 ; K=1024, N=256, f32 out ; A already bf16
__global__ __launch_bounds__(256) void k_h2_m(const u16* __restrict__ A,
                                              const uint4* __restrict__ Bpack,
                                              float* __restrict__ C){
  const int tid = threadIdx.x;
  const int mBase = blockIdx.x * 64, nBase = blockIdx.y * 64;
  const int ls = tid & 63;
  const int gm = mBase + (tid >> 6) * 16 + (ls & 15);
  const u16* ra = A + (size_t)gm * 1024 + (ls >> 4) * 8;
  f4_t acc[2][2] = {};
  gemm_core(32, Bpack, acc, [&](int kt) -> uint4 {
    return *(const uint4*)(ra + kt * 32);
  });
  const int wave = tid >> 6, lane = tid & 63;
  const int rbase = mBase + (wave >> 1) * 32 + ((lane >> 4) << 2);
  const int cbase = nBase + (wave & 1) * 32 + (lane & 15);
  #pragma unroll
  for (int i = 0; i < 2; i++)
    #pragma unroll
    for (int r = 0; r < 4; r++){
      int row = rbase + i * 16 + r;
      C[(size_t)row * 256 + cbase]      = acc[i][0][r];
      C[(size_t)row * 256 + cbase + 16] = acc[i][1][r];
    }
}

// ---------- GEMM 4 (MFMA): gates = concat(p,q,r,x2) @ W_ih^T + bih + bhh ; K=1024, N=1024, bf16 out
__global__ __launch_bounds__(256) void k_gates_m(
    const float* __restrict__ emb_p, const float* __restrict__ emb_q, const float* __restrict__ emb_r,
    const int* __restrict__ p, const int* __restrict__ q, const int* __restrict__ r,
    const float* __restrict__ x2, const uint4* __restrict__ Bpack,
    const float* __restrict__ bih, const float* __restrict__ bhh, u16* __restrict__ Cb){
  const int tid = threadIdx.x;
  const int mBase = blockIdx.x * 64, nBase = blockIdx.y * 64;
  const int ls = tid & 63;
  const int gm = mBase + (tid >> 6) * 16 + (ls & 15);
  const int kqoff = (ls >> 4) * 8;
  const float* s0 = emb_p + (size_t)p[gm] * 256 + kqoff;
  const float* s1 = emb_q + (size_t)q[gm] * 256 + kqoff;
  const float* s2 = emb_r + (size_t)r[gm] * 256 + kqoff;
  const float* s3 = x2 + (size_t)gm * 256 + kqoff;
  f4_t acc[2][2] = {};
  gemm_core(32, Bpack, acc, [&](int kt) -> uint4 {
    int kb = kt * 32;
    int seg = kb >> 8, ko = kb & 255;
    const float* s = (seg == 0) ? s0 : ((seg == 1) ? s1 : ((seg == 2) ? s2 : s3));
    float4 v0 = *(const float4*)(s + ko);
    float4 v1 = *(const float4*)(s + ko + 4);
    uint4 o; o.x = pk2bf(v0.x, v0.y); o.y = pk2bf(v0.z, v0.w);
    o.z = pk2bf(v1.x, v1.y); o.w = pk2bf(v1.z, v1.w);
    return o;
  });
  const int wave = tid >> 6, lane = tid & 63;
  const int rbase = mBase + (wave >> 1) * 32 + ((lane >> 4) << 2);
  const int cbase = nBase + (wave & 1) * 32 + (lane & 15);
  float b0 = bih[cbase] + bhh[cbase];
  float b1 = bih[cbase + 16] + bhh[cbase + 16];
  #pragma unroll
  for (int i = 0; i < 2; i++)
    #pragma unroll
    for (int r2 = 0; r2 < 4; r2++){
      int row = rbase + i * 16 + r2;
      Cb[(size_t)row * 1024 + cbase]      = f2bf(acc[i][0][r2] + b0);
      Cb[(size_t)row * 1024 + cbase + 16] = f2bf(acc[i][1][r2] + b1);
    }
}

// ---------- es/ed: per (m,h) dots of h-row with a_src / a_dst ; one wave per w = m*H+h
__global__ __launch_bounds__(256) void k_esed(
    const u16* __restrict__ hb, const float* __restrict__ hf,
    const float* __restrict__ asrc, const float* __restrict__ adst,
    float* __restrict__ es, float* __restrict__ ed, int Hm1, int Fo){
  int w = blockIdx.x * 4 + (threadIdx.x >> 6);
  int lane = threadIdx.x & 63;
  int h = w & Hm1;
  size_t base = (size_t)w * Fo;
  float s = 0.f, d = 0.f;
  for (int f = lane; f < Fo; f += 64){
    float hv = hb ? bf2f(hb[base + f]) : hf[base + f];
    s += hv * asrc[h * Fo + f];
    d += hv * adst[h * Fo + f];
  }
  s = wred(s); d = wred(d);
  if (!lane){ es[w] = s; ed[w] = d; }
}

// ---------- GAT aggregation: segment softmax (deg<=3) + weighted sum + bias (+ELU)
__global__ __launch_bounds__(256) void k_gatagg(
    const u16* __restrict__ hb, const float* __restrict__ hf,
    const float* __restrict__ es, const float* __restrict__ ed,
    const int* __restrict__ deg, const int* __restrict__ insrc,
    const float* __restrict__ bias, u16* __restrict__ outb, float* __restrict__ outf,
    int H, int foShift, int HFo, int do_elu){
  int m = blockIdx.x;
  int b = m / NN;
  int n = m - b * NN;
  int dg = deg[n];
  int s0 = insrc[n * 4 + 0];
  int s1 = insrc[n * 4 + 1];
  int s2 = insrc[n * 4 + 2];
  int rowBase = b * NN;
  for (int c = threadIdx.x; c < HFo; c += 256){
    int h = c >> foShift;
    float edv = ed[(size_t)m * H + h];
    float sc0 = es[(size_t)(rowBase + s0) * H + h] + edv;
    sc0 = (sc0 >= 0.f) ? sc0 : 0.2f * sc0;
    float sc1 = 0.f, sc2 = 0.f, mx = sc0;
    if (dg > 1){ sc1 = es[(size_t)(rowBase + s1) * H + h] + edv; sc1 = (sc1 >= 0.f) ? sc1 : 0.2f * sc1; mx = fmaxf(mx, sc1); }
    if (dg > 2){ sc2 = es[(size_t)(rowBase + s2) * H + h] + edv; sc2 = (sc2 >= 0.f) ? sc2 : 0.2f * sc2; mx = fmaxf(mx, sc2); }
    float e0 = __expf(sc0 - mx), e1 = 0.f, e2 = 0.f;
    if (dg > 1) e1 = __expf(sc1 - mx);
    if (dg > 2) e2 = __expf(sc2 - mx);
    float inv = 1.f / (e0 + e1 + e2);
    size_t c0 = (size_t)(rowBase + s0) * HFo + c;
    float acc = e0 * (hb ? bf2f(hb[c0]) : hf[c0]);
    if (dg > 1){ size_t c1 = (size_t)(rowBase + s1) * HFo + c; acc += e1 * (hb ? bf2f(hb[c1]) : hf[c1]); }
    if (dg > 2){ size_t c2 = (size_t)(rowBase + s2) * HFo + c; acc += e2 * (hb ? bf2f(hb[c2]) : hf[c2]); }
    acc *= inv;
    float o = acc + bias[c];
    if (do_elu) o = (o > 0.f) ? o : (__expf(o) - 1.f);
    if (outb) outb[(size_t)m * HFo + c] = f2bf(o);
    else      outf[(size_t)m * HFo + c] = o;
  }
}

// ---------- LSTM recurrence v9: one block per batch element, 1024 threads, 1 block/CU
// __launch_bounds__(1024, 4): 4 waves/EU => 1 block/CU => 128-VGPR budget so wreg stays resident.
// thread t = (gate g = t>>8, unit u = t&255); dot(h, W_hh[t][:]) via dot2.
// Weight chunks: kc 0..17 in VGPRs (72 VGPRs), kc 18..26 in LDS (144 KB), kc 27..31 streamed.
// h redistributed via one lane-distributed ds_read_b128 + v_readlane (VALU pipe).
#define KREG 18
#define KLDS 9
__global__ __launch_bounds__(1024, 4) void k_lstm(const u16* __restrict__ gates,
                                                  const uint4* __restrict__ whh4,
                                                  float* __restrict__ h_all){
  __shared__ __align__(16) uint4 wlds[KLDS][1024];   // 144 KB weight cache (kc KREG..KREG+KLDS-1)
  __shared__ __align__(16) u32 h2_lds[128];          // 256 bf16 h values, packed 2 per u32
  __shared__ float dots[1024];
  const int b = blockIdx.x, t = threadIdx.x;
  const int lane = t & 63;
  float c = 0.f;
  if (t < 128) h2_lds[t] = 0;
  uint4 wreg[KREG];
  #pragma unroll
  for (int kc = 0; kc < KREG; kc++) wreg[kc] = whh4[kc * 1024 + t];
  #pragma unroll
  for (int kc = 0; kc < KLDS; kc++) wlds[kc][t] = whh4[(KREG + kc) * 1024 + t];
  __syncthreads();
  const u16* gb = gates + (size_t)b * NN * 1024;
  const uint4* wbase = whh4 + (KREG + KLDS) * 1024 + t;
  for (int n = 0; n < NN; n++){
    // lane-distributed h read: lane L (L=lane&31) holds h u32s [4L, 4L+4) as .x...w
    uint4 hvec = *(const uint4*)&h2_lds[(lane & 31) * 4];
    float acc0 = bf2f(gb[(size_t)n * 1024 + t]);
    float acc1 = 0.f;
    // streamed chunks kc = KREG+KLDS .. 31
    #pragma unroll
    for (int i = 0; i < 32 - KREG - KLDS; i++){
      const int kc = KREG + KLDS + i;
      uint4 w = wbase[i * 1024];
      u32 hx = (u32)__builtin_amdgcn_readlane((int)hvec.x, kc);
      u32 hy = (u32)__builtin_amdgcn_readlane((int)hvec.y, kc);
      u32 hz = (u32)__builtin_amdgcn_readlane((int)hvec.z, kc);
      u32 hw = (u32)__builtin_amdgcn_readlane((int)hvec.w, kc);
      acc0 = dot2bf(w.x, hx, acc0);
      acc1 = dot2bf(w.y, hy, acc1);
      acc0 = dot2bf(w.z, hz, acc0);
      acc1 = dot2bf(w.w, hw, acc1);
    }
    // LDS-cached chunks kc = KREG .. KREG+KLDS-1
    #pragma unroll
    for (int i = 0; i < KLDS; i++){
      const int kc = KREG + i;
      uint4 w = wlds[i][t];
      u32 hx = (u32)__builtin_amdgcn_readlane((int)hvec.x, kc);
      u32 hy = (u32)__builtin_amdgcn_readlane((int)hvec.y, kc);
      u32 hz = (u32)__builtin_amdgcn_readlane((int)hvec.z, kc);
      u32 hw = (u32)__builtin_amdgcn_readlane((int)hvec.w, kc);
      acc0 = dot2bf(w.x, hx, acc0);
      acc1 = dot2bf(w.y, hy, acc1);
      acc0 = dot2bf(w.z, hz, acc0);
      acc1 = dot2bf(w.w, hw, acc1);
    }
    // register-cached chunks kc = 0 .. KREG-1
    #pragma unroll
    for (int kc = 0; kc < KREG; kc++){
      uint4 w = wreg[kc];
      u32 hx = (u32)__builtin_amdgcn_readlane((int)hvec.x, kc);
      u32 hy = (u32)__builtin_amdgcn_readlane((int)hvec.y, kc);
      u32 hz = (u32)__builtin_amdgcn_readlane((int)hvec.z, kc);
      u32 hw = (u32)__builtin_amdgcn_readlane((int)hvec.w, kc);
      acc0 = dot2bf(w.x, hx, acc0);
      acc1 = dot2bf(w.y, hy, acc1);
      acc0 = dot2bf(w.z, hz, acc0);
      acc1 = dot2bf(w.w, hw, acc1);
    }
    dots[t] = acc0 + acc1;
    __syncthreads();
    if (t < 256){
      float ai = dots[t], af = dots[256 + t], ag = dots[512 + t], ao = dots[768 + t];
      c = sigf(af) * c + sigf(ai) * tanh_(ag);
      float h = sigf(ao) * tanh_(c);
      h_all[((size_t)b * NN + n) * 256 + t] = h;
      ((u16*)h2_lds)[t] = f2bf(h);
    }
    __syncthreads();
  }
}

// ---------- final: y = sigmoid(concat(h, qn_emb, pn_emb) @ W_out + b_out) ; one wave per row
__global__ __launch_bounds__(256) void k_out(const float* __restrict__ h_all,
    const float* __restrict__ emb_q, const float* __restrict__ emb_p,
    const int* __restrict__ qn, const int* __restrict__ pn,
    const float* __restrict__ Wo, const float* __restrict__ bo, float* __restrict__ y){
  int m = blockIdx.x * 4 + (threadIdx.x >> 6);
  int lane = threadIdx.x & 63;
  const float* hr = h_all + (size_t)m * 256;
  const float* rq = emb_q + (size_t)qn[m] * 256;
  const float* rp = emb_p + (size_t)pn[m] * 256;
  float acc = 0.f;
  #pragma unroll
  for (int f = 0; f < 256; f += 64){
    int d = f + lane;
    acc += hr[d] * Wo[d];
    acc += rq[d] * Wo[256 + d];
    acc += rp[d] * Wo[512 + d];
  }
  acc = wred(acc);
  if (!lane) y[m] = sigf(acc + bo[0]);
}

// ---------- launch ----------
extern "C" void kernel_launch(void* const* d_in, const int* in_sizes, int n_in,
                              void* d_out, int out_size, void* d_ws, size_t ws_size,
                              hipStream_t stream){
  (void)n_in; (void)out_size; (void)ws_size;
  const int* p    = (const int*)d_in[1];
  const int* q    = (const int*)d_in[2];
  const int* r    = (const int*)d_in[3];
  const int* aff  = (const int*)d_in[4];
  const int* qn   = (const int*)d_in[5];
  const int* pn   = (const int*)d_in[6];
  const int* src  = (const int*)d_in[7];
  const int* dst  = (const int*)d_in[8];
  const float* emb_p  = (const float*)d_in[9];
  const float* emb_q  = (const float*)d_in[10];
  const float* emb_r  = (const float*)d_in[11];
  const float* emb_aff= (const float*)d_in[12];
  const float* W_aff  = (const float*)d_in[13];
  const float* b_aff  = (const float*)d_in[14];
  const float* W_g1   = (const float*)d_in[15];
  const float* a_s1   = (const float*)d_in[16];
  const float* a_d1   = (const float*)d_in[17];
  const float* b_g1   = (const float*)d_in[18];
  const float* W_g2   = (const float*)d_in[19];
  const float* a_s2   = (const float*)d_in[20];
  const float* a_d2   = (const float*)d_in[21];
  const float* b_g2   = (const float*)d_in[22];
  const float* W_ih   = (const float*)d_in[23];
  const float* W_hh   = (const float*)d_in[24];
  const float* b_ih   = (const float*)d_in[25];
  const float* b_hh   = (const float*)d_in[26];
  const float* W_out  = (const float*)d_in[27];
  const float* b_out  = (const float*)d_in[28];
  const int E = in_sizes[7];

  char* ws = (char*)d_ws;
  size_t off = 0;
  auto alloc = [&](size_t bytes){ size_t ret = off; off += (bytes + 255) & ~(size_t)255; return ret; };
  size_t o_bigA = alloc((size_t)MTOT * 1024 * 2);   // h1 bf16 -> gates bf16
  size_t o_bigB = alloc((size_t)MTOT * 1024 * 2);   // g1out bf16 -> x2 f32
  size_t o_buf3 = alloc((size_t)MTOT * 256 * 4);    // x0 -> h2 -> h_all
  size_t o_es1 = alloc((size_t)MTOT * 8 * 4);
  size_t o_ed1 = alloc((size_t)MTOT * 8 * 4);
  size_t o_es2 = alloc((size_t)MTOT * 4);
  size_t o_ed2 = alloc((size_t)MTOT * 4);
  size_t o_whh = alloc((size_t)32 * 1024 * 16);
  size_t o_deg = alloc(512 * 4);
  size_t o_ins = alloc((size_t)NN * 4 * 4);
  size_t o_bpih  = alloc((size_t)131072 * 16);   // W_ih^T pack (K=1024,N=1024)
  size_t o_bpg1  = alloc((size_t)32768 * 16);    // W_g1 pack (K=256,N=1024)
  size_t o_bpg2  = alloc((size_t)32768 * 16);    // W_g2 pack (K=1024,N=256)
  size_t o_bpaff = alloc((size_t)16384 * 16);    // W_affcat pack (K=512,N=256)

  u16*   h1    = (u16*)(ws + o_bigA);
  u16*   gates = (u16*)(ws + o_bigA);
  u16*   g1out = (u16*)(ws + o_bigB);
  float* x2    = (float*)(ws + o_bigB);
  float* x0    = (float*)(ws + o_buf3);
  float* h2    = (float*)(ws + o_buf3);
  float* h_all = (float*)(ws + o_buf3);
  float* es1   = (float*)(ws + o_es1);
  float* ed1   = (float*)(ws + o_ed1);
  float* es2   = (float*)(ws + o_es2);
  float* ed2   = (float*)(ws + o_ed2);
  uint4* whh4  = (uint4*)(ws + o_whh);
  int*   degp  = (int*)(ws + o_deg);
  int*   insp  = (int*)(ws + o_ins);
  u16*   bpih  = (u16*)(ws + o_bpih);
  u16*   bpg1  = (u16*)(ws + o_bpg1);
  u16*   bpg2  = (u16*)(ws + o_bpg2);
  u16*   bpaff = (u16*)(ws + o_bpaff);

  k_csr<<<1, 256, 0, stream>>>(src, dst, E, degp, insp);
  k_packwhh<<<128, 256, 0, stream>>>(W_hh, whh4);
  k_packB<<<512, 256, 0, stream>>>(W_ih, bpih, 1024, 1024, 1);
  k_packB<<<128, 256, 0, stream>>>(W_g1, bpg1, 256, 1024, 0);
  k_packB<<<128, 256, 0, stream>>>(W_g2, bpg2, 1024, 256, 0);
  k_packB<<<64, 256, 0, stream>>>(W_aff, bpaff, 512, 256, 0);

  k_affcat_m<<<dim3(NN, 4), 256, 0, stream>>>(emb_p, emb_aff, p, aff,
                                              (const uint4*)bpaff, b_aff, x0);
  k_h1_m<<<dim3(NN, 16), 256, 0, stream>>>(x0, (const uint4*)bpg1, h1);
  k_esed<<<(MTOT * 8) / 4, 256, 0, stream>>>(h1, nullptr, a_s1, a_d1, es1, ed1, 7, 128);
  k_gatagg<<<MTOT, 256, 0, stream>>>(h1, nullptr, es1, ed1, degp, insp, b_g1,
                                     g1out, nullptr, 8, 7, 1024, 1);
  k_h2_m<<<dim3(NN, 4), 256, 0, stream>>>(g1out, (const uint4*)bpg2, h2);
  k_esed<<<MTOT / 4, 256, 0, stream>>>(nullptr, h2, a_s2, a_d2, es2, ed2, 0, 256);
  k_gatagg<<<MTOT, 256, 0, stream>>>(nullptr, h2, es2, ed2, degp, insp, b_g2,
                                     nullptr, x2, 1, 8, 256, 0);
  k_gates_m<<<dim3(NN, 16), 256, 0, stream>>>(emb_p, emb_q, emb_r, p, q, r, x2,
                                              (const uint4*)bpih, b_ih, b_hh, gates);
  k_lstm<<<BB, 1024, 0, stream>>>(gates, whh4, h_all);
  k_out<<<MTOT / 4, 256, 0, stream>>>(h_all, emb_q, emb_p, qn, pn, W_out, b_out, (float*)d_out);
}

// Round 15
// 1797.231 us; speedup vs baseline: 1.1084x; 1.1084x over previous
//
#include <hip/hip_runtime.h>
#include <hip/hip_bf16.h>

typedef unsigned int u32;
typedef unsigned short u16;

#define MTOT 31936      // B*N = 64*499
#define NN 499
#define BB 64

// ---------- helpers ----------
__device__ __forceinline__ float lo16(u32 u){ return __uint_as_float(u << 16); }
__device__ __forceinline__ float hi16(u32 u){ return __uint_as_float(u & 0xffff0000u); }
__device__ __forceinline__ float bf2f(u16 u){ return __uint_as_float(((u32)u) << 16); }
__device__ __forceinline__ u16 f2bf(float f){
  u32 x = __float_as_uint(f);
  u32 r = (x + 0x7fffu + ((x >> 16) & 1u)) >> 16;   // RNE
  return (u16)r;
}
__device__ __forceinline__ float sigf(float x){ return 1.f / (1.f + __expf(-x)); }
__device__ __forceinline__ float tanh_(float x){ return 2.f * sigf(2.f * x) - 1.f; }
__device__ __forceinline__ float wred(float v){
  #pragma unroll
  for (int off = 32; off; off >>= 1) v += __shfl_down(v, off, 64);
  return v;
}

// packed bf16 pair dot: acc += lo(w)*lo(h) + hi(w)*hi(h)
typedef __attribute__((ext_vector_type(2))) __bf16 bf16x2;
#if __has_builtin(__builtin_amdgcn_fdot2_f32_bf16)
__device__ __forceinline__ float dot2bf(u32 w, u32 h, float acc){
  union { u32 u; bf16x2 v; } uw, uh;
  uw.u = w; uh.u = h;
  return __builtin_amdgcn_fdot2_f32_bf16(uw.v, uh.v, acc, false);
}
#else
__device__ __forceinline__ float dot2bf(u32 w, u32 h, float acc){
  return acc + lo16(w) * lo16(h) + hi16(w) * hi16(h);
}
#endif

// pack two f32 -> u32 of two bf16 (RNE)
#if __has_builtin(__builtin_amdgcn_cvt_pk_bf16_f32)
__device__ __forceinline__ u32 pk2bf(float a, float b){
  union { bf16x2 v; u32 u; } r;
  r.v = __builtin_amdgcn_cvt_pk_bf16_f32(a, b);
  return r.u;
}
#else
__device__ __forceinline__ u32 pk2bf(float a, float b){
  return (u32)f2bf(a) | ((u32)f2bf(b) << 16);
}
#endif

// ---------- MFMA plumbing (16x16x32 bf16) ----------
// A-frag: lane holds A[m=lane&15][k=(lane>>4)*8 + j], j=0..7  (8 bf16 = uint4)
// B-frag: lane holds B[k=(lane>>4)*8 + j][n=lane&15]
// C/D   : reg r at row=(lane>>4)*4+r, col=lane&15
typedef __attribute__((ext_vector_type(8))) short bfrag8;
typedef __attribute__((ext_vector_type(4))) float f4_t;
union FragU { uint4 u; bfrag8 s; };

__device__ __forceinline__ f4_t mfma16(FragU a, FragU b, f4_t c){
  return __builtin_amdgcn_mfma_f32_16x16x32_bf16(a.s, b.s, c, 0, 0, 0);
}

// GEMM core v2: 64M x 128N tile, 4 waves; wave w covers N cols [w*32, w*32+32).
// A (64Mx32K per kt) staged in LDS (double-buffered, one barrier/kt); B frags direct from global.
template <typename AL>
__device__ __forceinline__ void gemm_core2(int K32, const uint4* __restrict__ Bpack,
                                           f4_t (&acc)[4][2], AL aload){
  __shared__ __align__(16) uint4 As[2][256];
  const int tid = threadIdx.x;
  const int wave = tid >> 6, lane = tid & 63;
  const uint4* Bp0 = Bpack + ((size_t)(blockIdx.y * 8 + wave * 2) * K32) * 64 + lane;
  const uint4* Bp1 = Bp0 + (size_t)K32 * 64;
  int buf = 0;
  for (int kt = 0; kt < K32; kt++){
    FragU b0, b1;
    b0.u = Bp0[kt * 64];
    b1.u = Bp1[kt * 64];
    As[buf][tid] = aload(kt);
    __syncthreads();
    FragU a0, a1, a2, a3;
    a0.u = As[buf][lane];
    a1.u = As[buf][64 + lane];
    a2.u = As[buf][128 + lane];
    a3.u = As[buf][192 + lane];
    acc[0][0] = mfma16(a0, b0, acc[0][0]); acc[0][1] = mfma16(a0, b1, acc[0][1]);
    acc[1][0] = mfma16(a1, b0, acc[1][0]); acc[1][1] = mfma16(a1, b1, acc[1][1]);
    acc[2][0] = mfma16(a2, b0, acc[2][0]); acc[2][1] = mfma16(a2, b1, acc[2][1]);
    acc[3][0] = mfma16(a3, b0, acc[3][0]); acc[3][1] = mfma16(a3, b1, acc[3][1]);
    buf ^= 1;
  }
}

// ---------- prep: pack weight matrix into B-fragment-layout bf16 chunks ----------
// chunk c: nt=c/(K32*64), kt=(c/64)%K32, l=c&63 -> holds B[k=kt*32+(l>>4)*8+j][n=nt*16+(l&15)]
// trans=0: B[k][n] = W[k*N+n] ; trans=1: B[k][n] = W[n*K+k]
__global__ __launch_bounds__(256) void k_packB(const float* __restrict__ W, u16* __restrict__ out,
                                               int K, int N, int trans){
  int c = blockIdx.x * 256 + threadIdx.x;
  int K32 = K >> 5;
  int total = (N >> 4) * K32 * 64;
  if (c >= total) return;
  int l = c & 63;
  int rem = c >> 6;
  int kt = rem % K32, nt = rem / K32;
  int n = nt * 16 + (l & 15);
  int kb = kt * 32 + (l >> 4) * 8;
  u32 ov[4];
  #pragma unroll
  for (int j2 = 0; j2 < 4; j2++){
    int k = kb + j2 * 2;
    float f0 = trans ? W[(size_t)n * K + k]     : W[(size_t)k * N + n];
    float f1 = trans ? W[(size_t)n * K + k + 1] : W[(size_t)(k + 1) * N + n];
    ov[j2] = pk2bf(f0, f1);
  }
  uint4 o; o.x = ov[0]; o.y = ov[1]; o.z = ov[2]; o.w = ov[3];
  *(uint4*)(out + (size_t)c * 8) = o;
}

// ---------- CSR build (chain graph, in-degree <= 3) ----------
__global__ void k_csr(const int* __restrict__ src, const int* __restrict__ dst, int E,
                      int* __restrict__ deg, int* __restrict__ insrc){
  int tid = threadIdx.x;
  for (int i = tid; i < NN; i += 256) deg[i] = 0;
  for (int i = tid; i < NN * 4; i += 256) insrc[i] = 0;
  __syncthreads();
  for (int e = tid; e < E; e += 256){
    int d = dst[e];
    int slot = atomicAdd(&deg[d], 1);
    if (slot < 4) insrc[d * 4 + slot] = src[e];
  }
}

// ---------- pack W_hh [1024,256] f32 -> bf16 uint4 chunks: whh4[kc*1024 + j] = row j, k = kc*8..+7
__global__ void k_packwhh(const float* __restrict__ Whh, uint4* __restrict__ whh4){
  int idx = blockIdx.x * 256 + threadIdx.x;      // 32768 total
  int j = idx & 1023, kc = idx >> 10;
  const float* w = Whh + (size_t)j * 256 + kc * 8;
  float4 w0 = *(const float4*)w;
  float4 w1 = *(const float4*)(w + 4);
  uint4 o;
  o.x = pk2bf(w0.x, w0.y);
  o.y = pk2bf(w0.z, w0.w);
  o.z = pk2bf(w1.x, w1.y);
  o.w = pk2bf(w1.z, w1.w);
  whh4[kc * 1024 + j] = o;
}

// ---------- GEMM 1 (MFMA): x0 = concat(emb_p[p], emb_aff[aff]) @ W_affcat + b ; K=512, N=256, f32 out
__global__ __launch_bounds__(256) void k_affcat_m(
    const float* __restrict__ emb_p, const float* __restrict__ emb_aff,
    const int* __restrict__ p, const int* __restrict__ aff,
    const uint4* __restrict__ Bpack, const float* __restrict__ bias, float* __restrict__ C){
  const int tid = threadIdx.x;
  const int mBase = blockIdx.x * 64, nBase = blockIdx.y * 128;
  const int ls = tid & 63;
  const int gm = mBase + (tid >> 6) * 16 + (ls & 15);
  const int kqoff = (ls >> 4) * 8;
  const float* rp = emb_p + (size_t)p[gm] * 256 + kqoff;
  const float* ra = emb_aff + (size_t)aff[gm] * 256 + kqoff;
  f4_t acc[4][2] = {};
  gemm_core2(16, Bpack, acc, [&](int kt) -> uint4 {
    int kb = kt * 32;
    const float* s = (kb < 256) ? (rp + kb) : (ra + kb - 256);
    float4 v0 = *(const float4*)s;
    float4 v1 = *(const float4*)(s + 4);
    uint4 o; o.x = pk2bf(v0.x, v0.y); o.y = pk2bf(v0.z, v0.w);
    o.z = pk2bf(v1.x, v1.y); o.w = pk2bf(v1.z, v1.w);
    return o;
  });
  const int wave = tid >> 6, lane = tid & 63;
  const int rb = (lane >> 4) << 2;
  const int cbase = nBase + wave * 32 + (lane & 15);
  float b0 = bias[cbase], b1 = bias[cbase + 16];
  #pragma unroll
  for (int i = 0; i < 4; i++)
    #pragma unroll
    for (int r = 0; r < 4; r++){
      int row = mBase + i * 16 + rb + r;
      C[(size_t)row * 256 + cbase]      = acc[i][0][r] + b0;
      C[(size_t)row * 256 + cbase + 16] = acc[i][1][r] + b1;
    }
}

// ---------- GEMM 2 (MFMA): h1 = x0 @ W_g1 ; K=256, N=1024, bf16 out
__global__ __launch_bounds__(256) void k_h1_m(const float* __restrict__ A,
                                              const uint4* __restrict__ Bpack,
                                              u16* __restrict__ Cb){
  const int tid = threadIdx.x;
  const int mBase = blockIdx.x * 64, nBase = blockIdx.y * 128;
  const int ls = tid & 63;
  const int gm = mBase + (tid >> 6) * 16 + (ls & 15);
  const float* ra = A + (size_t)gm * 256 + (ls >> 4) * 8;
  f4_t acc[4][2] = {};
  gemm_core2(8, Bpack, acc, [&](int kt) -> uint4 {
    const float* s = ra + kt * 32;
    float4 v0 = *(const float4*)s;
    float4 v1 = *(const float4*)(s + 4);
    uint4 o; o.x = pk2bf(v0.x, v0.y); o.y = pk2bf(v0.z, v0.w);
    o.z = pk2bf(v1.x, v1.y); o.w = pk2bf(v1.z, v1.w);
    return o;
  });
  const int wave = tid >> 6, lane = tid & 63;
  const int rb = (lane >> 4) << 2;
  const int cbase = nBase + wave * 32 + (lane & 15);
  #pragma unroll
  for (int i = 0; i < 4; i++)
    #pragma unroll
    for (int r = 0; r < 4; r++){
      int row = mBase + i * 16 + rb + r;
      Cb[(size_t)row * 1024 + cbase]      = f2bf(acc[i][0][r]);
      Cb[(size_t)row * 1024 + cbase + 16] = f2bf(acc[i][1][r]);
    }
}

// ---------- GEMM 3 (MFMA): h2 = g1out @ W_g2 ; K=1024, N=256, f32 out ; A already bf16
__global__ __launch_bounds__(256) void k_h2_m(const u16* __restrict__ A,
                                              const uint4* __restrict__ Bpack,
                                              float* __restrict__ C){
  const int tid = threadIdx.x;
  const int mBase = blockIdx.x * 64, nBase = blockIdx.y * 128;
  const int ls = tid & 63;
  const int gm = mBase + (tid >> 6) * 16 + (ls & 15);
  const u16* ra = A + (size_t)gm * 1024 + (ls >> 4) * 8;
  f4_t acc[4][2] = {};
  gemm_core2(32, Bpack, acc, [&](int kt) -> uint4 {
    return *(const uint4*)(ra + kt * 32);
  });
  const int wave = tid >> 6, lane = tid & 63;
  const int rb = (lane >> 4) << 2;
  const int cbase = nBase + wave * 32 + (lane & 15);
  #pragma unroll
  for (int i = 0; i < 4; i++)
    #pragma unroll
    for (int r = 0; r < 4; r++){
      int row = mBase + i * 16 + rb + r;
      C[(size_t)row * 256 + cbase]      = acc[i][0][r];
      C[(size_t)row * 256 + cbase + 16] = acc[i][1][r];
    }
}

// ---------- GEMM 4 (MFMA): gates = concat(p,q,r,x2) @ W_ih^T + bih + bhh ; K=1024, N=1024, bf16 out
__global__ __launch_bounds__(256) void k_gates_m(
    const float* __restrict__ emb_p, const float* __restrict__ emb_q, const float* __restrict__ emb_r,
    const int* __restrict__ p, const int* __restrict__ q, const int* __restrict__ r,
    const float* __restrict__ x2, const uint4* __restrict__ Bpack,
    const float* __restrict__ bih, const float* __restrict__ bhh, u16* __restrict__ Cb){
  const int tid = threadIdx.x;
  const int mBase = blockIdx.x * 64, nBase = blockIdx.y * 128;
  const int ls = tid & 63;
  const int gm = mBase + (tid >> 6) * 16 + (ls & 15);
  const int kqoff = (ls >> 4) * 8;
  const float* s0 = emb_p + (size_t)p[gm] * 256 + kqoff;
  const float* s1 = emb_q + (size_t)q[gm] * 256 + kqoff;
  const float* s2 = emb_r + (size_t)r[gm] * 256 + kqoff;
  const float* s3 = x2 + (size_t)gm * 256 + kqoff;
  f4_t acc[4][2] = {};
  gemm_core2(32, Bpack, acc, [&](int kt) -> uint4 {
    int kb = kt * 32;
    int seg = kb >> 8, ko = kb & 255;
    const float* s = (seg == 0) ? s0 : ((seg == 1) ? s1 : ((seg == 2) ? s2 : s3));
    float4 v0 = *(const float4*)(s + ko);
    float4 v1 = *(const float4*)(s + ko + 4);
    uint4 o; o.x = pk2bf(v0.x, v0.y); o.y = pk2bf(v0.z, v0.w);
    o.z = pk2bf(v1.x, v1.y); o.w = pk2bf(v1.z, v1.w);
    return o;
  });
  const int wave = tid >> 6, lane = tid & 63;
  const int rb = (lane >> 4) << 2;
  const int cbase = nBase + wave * 32 + (lane & 15);
  float b0 = bih[cbase] + bhh[cbase];
  float b1 = bih[cbase + 16] + bhh[cbase + 16];
  #pragma unroll
  for (int i = 0; i < 4; i++)
    #pragma unroll
    for (int r2 = 0; r2 < 4; r2++){
      int row = mBase + i * 16 + rb + r2;
      Cb[(size_t)row * 1024 + cbase]      = f2bf(acc[i][0][r2] + b0);
      Cb[(size_t)row * 1024 + cbase + 16] = f2bf(acc[i][1][r2] + b1);
    }
}

// ---------- es/ed: per (m,h) dots of h-row with a_src / a_dst ; one wave per w = m*H+h
__global__ __launch_bounds__(256) void k_esed(
    const u16* __restrict__ hb, const float* __restrict__ hf,
    const float* __restrict__ asrc, const float* __restrict__ adst,
    float* __restrict__ es, float* __restrict__ ed, int Hm1, int Fo){
  int w = blockIdx.x * 4 + (threadIdx.x >> 6);
  int lane = threadIdx.x & 63;
  int h = w & Hm1;
  size_t base = (size_t)w * Fo;
  float s = 0.f, d = 0.f;
  for (int f = lane; f < Fo; f += 64){
    float hv = hb ? bf2f(hb[base + f]) : hf[base + f];
    s += hv * asrc[h * Fo + f];
    d += hv * adst[h * Fo + f];
  }
  s = wred(s); d = wred(d);
  if (!lane){ es[w] = s; ed[w] = d; }
}

// ---------- GAT aggregation: segment softmax (deg<=3) + weighted sum + bias (+ELU)
__global__ __launch_bounds__(256) void k_gatagg(
    const u16* __restrict__ hb, const float* __restrict__ hf,
    const float* __restrict__ es, const float* __restrict__ ed,
    const int* __restrict__ deg, const int* __restrict__ insrc,
    const float* __restrict__ bias, u16* __restrict__ outb, float* __restrict__ outf,
    int H, int foShift, int HFo, int do_elu){
  int m = blockIdx.x;
  int b = m / NN;
  int n = m - b * NN;
  int dg = deg[n];
  int s0 = insrc[n * 4 + 0];
  int s1 = insrc[n * 4 + 1];
  int s2 = insrc[n * 4 + 2];
  int rowBase = b * NN;
  for (int c = threadIdx.x; c < HFo; c += 256){
    int h = c >> foShift;
    float edv = ed[(size_t)m * H + h];
    float sc0 = es[(size_t)(rowBase + s0) * H + h] + edv;
    sc0 = (sc0 >= 0.f) ? sc0 : 0.2f * sc0;
    float sc1 = 0.f, sc2 = 0.f, mx = sc0;
    if (dg > 1){ sc1 = es[(size_t)(rowBase + s1) * H + h] + edv; sc1 = (sc1 >= 0.f) ? sc1 : 0.2f * sc1; mx = fmaxf(mx, sc1); }
    if (dg > 2){ sc2 = es[(size_t)(rowBase + s2) * H + h] + edv; sc2 = (sc2 >= 0.f) ? sc2 : 0.2f * sc2; mx = fmaxf(mx, sc2); }
    float e0 = __expf(sc0 - mx), e1 = 0.f, e2 = 0.f;
    if (dg > 1) e1 = __expf(sc1 - mx);
    if (dg > 2) e2 = __expf(sc2 - mx);
    float inv = 1.f / (e0 + e1 + e2);
    size_t c0 = (size_t)(rowBase + s0) * HFo + c;
    float acc = e0 * (hb ? bf2f(hb[c0]) : hf[c0]);
    if (dg > 1){ size_t c1 = (size_t)(rowBase + s1) * HFo + c; acc += e1 * (hb ? bf2f(hb[c1]) : hf[c1]); }
    if (dg > 2){ size_t c2 = (size_t)(rowBase + s2) * HFo + c; acc += e2 * (hb ? bf2f(hb[c2]) : hf[c2]); }
    acc *= inv;
    float o = acc + bias[c];
    if (do_elu) o = (o > 0.f) ? o : (__expf(o) - 1.f);
    if (outb) outb[(size_t)m * HFo + c] = f2bf(o);
    else      outf[(size_t)m * HFo + c] = o;
  }
}

// ---------- LSTM recurrence v10: one block per batch element, 1024 threads, 1 block/CU
// amdgpu_waves_per_eu(1,4): min-occupancy 1 wave/EU -> register budget up to 512 so wreg
// (18 uint4 = 72 VGPRs) can stay in arch VGPRs instead of AGPR round-trips.
// thread t = (gate g = t>>8, unit u = t&255); dot(h, W_hh[t][:]) via dot2.
// Weight chunks: kc 0..17 in VGPRs, kc 18..26 in LDS (144 KB), kc 27..31 streamed.
// h redistributed via one lane-distributed ds_read_b128 + v_readlane (VALU pipe).
#define KREG 18
#define KLDS 9
__global__ __launch_bounds__(1024)
__attribute__((amdgpu_waves_per_eu(1, 4)))
void k_lstm(const u16* __restrict__ gates,
            const uint4* __restrict__ whh4,
            float* __restrict__ h_all){
  __shared__ __align__(16) uint4 wlds[KLDS][1024];   // 144 KB weight cache (kc KREG..KREG+KLDS-1)
  __shared__ __align__(16) u32 h2_lds[128];          // 256 bf16 h values, packed 2 per u32
  __shared__ float dots[1024];
  const int b = blockIdx.x, t = threadIdx.x;
  const int lane = t & 63;
  float c = 0.f;
  if (t < 128) h2_lds[t] = 0;
  uint4 wreg[KREG];
  #pragma unroll
  for (int kc = 0; kc < KREG; kc++) wreg[kc] = whh4[kc * 1024 + t];
  #pragma unroll
  for (int kc = 0; kc < KLDS; kc++) wlds[kc][t] = whh4[(KREG + kc) * 1024 + t];
  __syncthreads();
  const u16* gb = gates + (size_t)b * NN * 1024;
  const uint4* wbase = whh4 + (KREG + KLDS) * 1024 + t;
  for (int n = 0; n < NN; n++){
    // lane-distributed h read: lane L (L=lane&31) holds h u32s [4L, 4L+4) as .x...w
    uint4 hvec = *(const uint4*)&h2_lds[(lane & 31) * 4];
    float acc0 = bf2f(gb[(size_t)n * 1024 + t]);
    float acc1 = 0.f;
    // streamed chunks kc = KREG+KLDS .. 31
    #pragma unroll
    for (int i = 0; i < 32 - KREG - KLDS; i++){
      const int kc = KREG + KLDS + i;
      uint4 w = wbase[i * 1024];
      u32 hx = (u32)__builtin_amdgcn_readlane((int)hvec.x, kc);
      u32 hy = (u32)__builtin_amdgcn_readlane((int)hvec.y, kc);
      u32 hz = (u32)__builtin_amdgcn_readlane((int)hvec.z, kc);
      u32 hw = (u32)__builtin_amdgcn_readlane((int)hvec.w, kc);
      acc0 = dot2bf(w.x, hx, acc0);
      acc1 = dot2bf(w.y, hy, acc1);
      acc0 = dot2bf(w.z, hz, acc0);
      acc1 = dot2bf(w.w, hw, acc1);
    }
    // LDS-cached chunks kc = KREG .. KREG+KLDS-1
    #pragma unroll
    for (int i = 0; i < KLDS; i++){
      const int kc = KREG + i;
      uint4 w = wlds[i][t];
      u32 hx = (u32)__builtin_amdgcn_readlane((int)hvec.x, kc);
      u32 hy = (u32)__builtin_amdgcn_readlane((int)hvec.y, kc);
      u32 hz = (u32)__builtin_amdgcn_readlane((int)hvec.z, kc);
      u32 hw = (u32)__builtin_amdgcn_readlane((int)hvec.w, kc);
      acc0 = dot2bf(w.x, hx, acc0);
      acc1 = dot2bf(w.y, hy, acc1);
      acc0 = dot2bf(w.z, hz, acc0);
      acc1 = dot2bf(w.w, hw, acc1);
    }
    // register-cached chunks kc = 0 .. KREG-1
    #pragma unroll
    for (int kc = 0; kc < KREG; kc++){
      uint4 w = wreg[kc];
      u32 hx = (u32)__builtin_amdgcn_readlane((int)hvec.x, kc);
      u32 hy = (u32)__builtin_amdgcn_readlane((int)hvec.y, kc);
      u32 hz = (u32)__builtin_amdgcn_readlane((int)hvec.z, kc);
      u32 hw = (u32)__builtin_amdgcn_readlane((int)hvec.w, kc);
      acc0 = dot2bf(w.x, hx, acc0);
      acc1 = dot2bf(w.y, hy, acc1);
      acc0 = dot2bf(w.z, hz, acc0);
      acc1 = dot2bf(w.w, hw, acc1);
    }
    dots[t] = acc0 + acc1;
    __syncthreads();
    if (t < 256){
      float ai = dots[t], af = dots[256 + t], ag = dots[512 + t], ao = dots[768 + t];
      c = sigf(af) * c + sigf(ai) * tanh_(ag);
      float h = sigf(ao) * tanh_(c);
      h_all[((size_t)b * NN + n) * 256 + t] = h;
      ((u16*)h2_lds)[t] = f2bf(h);
    }
    __syncthreads();
  }
}

// ---------- final: y = sigmoid(concat(h, qn_emb, pn_emb) @ W_out + b_out) ; one wave per row
__global__ __launch_bounds__(256) void k_out(const float* __restrict__ h_all,
    const float* __restrict__ emb_q, const float* __restrict__ emb_p,
    const int* __restrict__ qn, const int* __restrict__ pn,
    const float* __restrict__ Wo, const float* __restrict__ bo, float* __restrict__ y){
  int m = blockIdx.x * 4 + (threadIdx.x >> 6);
  int lane = threadIdx.x & 63;
  const float* hr = h_all + (size_t)m * 256;
  const float* rq = emb_q + (size_t)qn[m] * 256;
  const float* rp = emb_p + (size_t)pn[m] * 256;
  float acc = 0.f;
  #pragma unroll
  for (int f = 0; f < 256; f += 64){
    int d = f + lane;
    acc += hr[d] * Wo[d];
    acc += rq[d] * Wo[256 + d];
    acc += rp[d] * Wo[512 + d];
  }
  acc = wred(acc);
  if (!lane) y[m] = sigf(acc + bo[0]);
}

// ---------- launch ----------
extern "C" void kernel_launch(void* const* d_in, const int* in_sizes, int n_in,
                              void* d_out, int out_size, void* d_ws, size_t ws_size,
                              hipStream_t stream){
  (void)n_in; (void)out_size; (void)ws_size;
  const int* p    = (const int*)d_in[1];
  const int* q    = (const int*)d_in[2];
  const int* r    = (const int*)d_in[3];
  const int* aff  = (const int*)d_in[4];
  const int* qn   = (const int*)d_in[5];
  const int* pn   = (const int*)d_in[6];
  const int* src  = (const int*)d_in[7];
  const int* dst  = (const int*)d_in[8];
  const float* emb_p  = (const float*)d_in[9];
  const float* emb_q  = (const float*)d_in[10];
  const float* emb_r  = (const float*)d_in[11];
  const float* emb_aff= (const float*)d_in[12];
  const float* W_aff  = (const float*)d_in[13];
  const float* b_aff  = (const float*)d_in[14];
  const float* W_g1   = (const float*)d_in[15];
  const float* a_s1   = (const float*)d_in[16];
  const float* a_d1   = (const float*)d_in[17];
  const float* b_g1   = (const float*)d_in[18];
  const float* W_g2   = (const float*)d_in[19];
  const float* a_s2   = (const float*)d_in[20];
  const float* a_d2   = (const float*)d_in[21];
  const float* b_g2   = (const float*)d_in[22];
  const float* W_ih   = (const float*)d_in[23];
  const float* W_hh   = (const float*)d_in[24];
  const float* b_ih   = (const float*)d_in[25];
  const float* b_hh   = (const float*)d_in[26];
  const float* W_out  = (const float*)d_in[27];
  const float* b_out  = (const float*)d_in[28];
  const int E = in_sizes[7];

  char* ws = (char*)d_ws;
  size_t off = 0;
  auto alloc = [&](size_t bytes){ size_t ret = off; off += (bytes + 255) & ~(size_t)255; return ret; };
  size_t o_bigA = alloc((size_t)MTOT * 1024 * 2);   // h1 bf16 -> gates bf16
  size_t o_bigB = alloc((size_t)MTOT * 1024 * 2);   // g1out bf16 -> x2 f32
  size_t o_buf3 = alloc((size_t)MTOT * 256 * 4);    // x0 -> h2 -> h_all
  size_t o_es1 = alloc((size_t)MTOT * 8 * 4);
  size_t o_ed1 = alloc((size_t)MTOT * 8 * 4);
  size_t o_es2 = alloc((size_t)MTOT * 4);
  size_t o_ed2 = alloc((size_t)MTOT * 4);
  size_t o_whh = alloc((size_t)32 * 1024 * 16);
  size_t o_deg = alloc(512 * 4);
  size_t o_ins = alloc((size_t)NN * 4 * 4);
  size_t o_bpih  = alloc((size_t)131072 * 16);   // W_ih^T pack (K=1024,N=1024)
  size_t o_bpg1  = alloc((size_t)32768 * 16);    // W_g1 pack (K=256,N=1024)
  size_t o_bpg2  = alloc((size_t)32768 * 16);    // W_g2 pack (K=1024,N=256)
  size_t o_bpaff = alloc((size_t)16384 * 16);    // W_affcat pack (K=512,N=256)

  u16*   h1    = (u16*)(ws + o_bigA);
  u16*   gates = (u16*)(ws + o_bigA);
  u16*   g1out = (u16*)(ws + o_bigB);
  float* x2    = (float*)(ws + o_bigB);
  float* x0    = (float*)(ws + o_buf3);
  float* h2    = (float*)(ws + o_buf3);
  float* h_all = (float*)(ws + o_buf3);
  float* es1   = (float*)(ws + o_es1);
  float* ed1   = (float*)(ws + o_ed1);
  float* es2   = (float*)(ws + o_es2);
  float* ed2   = (float*)(ws + o_ed2);
  uint4* whh4  = (uint4*)(ws + o_whh);
  int*   degp  = (int*)(ws + o_deg);
  int*   insp  = (int*)(ws + o_ins);
  u16*   bpih  = (u16*)(ws + o_bpih);
  u16*   bpg1  = (u16*)(ws + o_bpg1);
  u16*   bpg2  = (u16*)(ws + o_bpg2);
  u16*   bpaff = (u16*)(ws + o_bpaff);

  k_csr<<<1, 256, 0, stream>>>(src, dst, E, degp, insp);
  k_packwhh<<<128, 256, 0, stream>>>(W_hh, whh4);
  k_packB<<<512, 256, 0, stream>>>(W_ih, bpih, 1024, 1024, 1);
  k_packB<<<128, 256, 0, stream>>>(W_g1, bpg1, 256, 1024, 0);
  k_packB<<<128, 256, 0, stream>>>(W_g2, bpg2, 1024, 256, 0);
  k_packB<<<64, 256, 0, stream>>>(W_aff, bpaff, 512, 256, 0);

  k_affcat_m<<<dim3(NN, 2), 256, 0, stream>>>(emb_p, emb_aff, p, aff,
                                              (const uint4*)bpaff, b_aff, x0);
  k_h1_m<<<dim3(NN, 8), 256, 0, stream>>>(x0, (const uint4*)bpg1, h1);
  k_esed<<<(MTOT * 8) / 4, 256, 0, stream>>>(h1, nullptr, a_s1, a_d1, es1, ed1, 7, 128);
  k_gatagg<<<MTOT, 256, 0, stream>>>(h1, nullptr, es1, ed1, degp, insp, b_g1,
                                     g1out, nullptr, 8, 7, 1024, 1);
  k_h2_m<<<dim3(NN, 2), 256, 0, stream>>>(g1out, (const uint4*)bpg2, h2);
  k_esed<<<MTOT / 4, 256, 0, stream>>>(nullptr, h2, a_s2, a_d2, es2, ed2, 0, 256);
  k_gatagg<<<MTOT, 256, 0, stream>>>(nullptr, h2, es2, ed2, degp, insp, b_g2,
                                     nullptr, x2, 1, 8, 256, 0);
  k_gates_m<<<dim3(NN, 8), 256, 0, stream>>>(emb_p, emb_q, emb_r, p, q, r, x2,
                                             (const uint4*)bpih, b_ih, b_hh, gates);
  k_lstm<<<BB, 1024, 0, stream>>>(gates, whh4, h_all);
  k_out<<<MTOT / 4, 256, 0, stream>>>(h_all, emb_q, emb_p, qn, pn, W_out, b_out, (float*)d_out);
}